// Round 14
// baseline (120.209 us; speedup 1.0000x reference)
//
#include <hip/hip_runtime.h>

#define TRE_EPS   0.01f
#define TRE_CAP   256
#define TRE_NB    2048   // 64 g-values * 32 r-values
#define TRE_PGRID 1024   // persistent blocks (4 per CU)

typedef float tre_f4 __attribute__((ext_vector_type(4)));
typedef short tre_bf8 __attribute__((ext_vector_type(8)));

__device__ __forceinline__ unsigned short tre_f2bf(float f) {
    unsigned int u = __float_as_uint(f);
    u += 0x7fffu + ((u >> 16) & 1u);           // RNE
    return (unsigned short)(u >> 16);
}
__device__ __forceinline__ unsigned long long tre_pack4(float a, float b,
                                                        float c, float d) {
    return (unsigned long long)tre_f2bf(a)
         | ((unsigned long long)tre_f2bf(b) << 16)
         | ((unsigned long long)tre_f2bf(c) << 32)
         | ((unsigned long long)tre_f2bf(d) << 48);
}

// ---------------------------------------------------------------------------
// Kernel 1: bin edges by (g, r) pair.  counts zeroed beforehand; seeds cursor.
__global__ __launch_bounds__(256) void tre_bin(
    const int* __restrict__ rm, int E,
    int* __restrict__ counts, int* __restrict__ list, int* __restrict__ cursor)
{
    if (blockIdx.x == 0 && threadIdx.x == 0) *cursor = TRE_PGRID;
    int e = blockIdx.x * 256 + threadIdx.x;
    if (e >= E) return;
    int g  = rm[2 * e + 0];
    int r2 = rm[2 * e + 1];
    int b  = (g << 5) | (r2 >> 1);
    int idx = atomicAdd(&counts[b], 1);
    if (idx < TRE_CAP)
        list[b * TRE_CAP + idx] = (e << 1) | (r2 & 1);
}

// M = Q[g]^T * RE[r] * Q[g] via bf16 MFMA; result -> mreg (thread's flat
// write-slice).  Uses sB (16 KB) with internal barriers.
__device__ __forceinline__ void tre_compute_M(
    int b, const float* __restrict__ Q, const float* __restrict__ RE,
    unsigned char* sB, int t, tre_f4 mreg[4])
{
    const int g = b >> 5;
    const int r = b & 31;
    const int lane = t & 63;
    const int wv = t >> 6;
    const int fr = lane & 15;
    const int fq = lane >> 4;
    const int i0 = wv << 4;

    const float* Qg  = Q  + ((size_t)g << 12);
    const float* REr = RE + ((size_t)r << 12);
    unsigned char* REb = sB;
    unsigned char* Qtb = sB + 8192;

    // stage RE -> bf16 row-major (swizzled)
    for (int i = t; i < 1024; i += 256) {
        float4 w = ((const float4*)REr)[i];
        int R = i >> 4, c0 = (i & 15) << 2;
        int o = c0 * 2;
        *(unsigned long long*)(REb + R * 128 + (o ^ ((R & 7) << 4))) =
            tre_pack4(w.x, w.y, w.z, w.w);
    }
    // stage Q^T -> bf16 (column-coalesced global reads)
    for (int it = 0; it < 4; ++it) {
        int k0 = (wv << 2) + (it << 4);
        float q0 = Qg[(k0 + 0) * 64 + lane];
        float q1 = Qg[(k0 + 1) * 64 + lane];
        float q2 = Qg[(k0 + 2) * 64 + lane];
        float q3 = Qg[(k0 + 3) * 64 + lane];
        int R = lane, o = k0 * 2;
        *(unsigned long long*)(Qtb + R * 128 + (o ^ ((R & 7) << 4))) =
            tre_pack4(q0, q1, q2, q3);
    }
    __syncthreads();

    // pass 1: A = RE * Q
    tre_f4 accA[4];
#pragma unroll
    for (int jf = 0; jf < 4; ++jf) accA[jf] = (tre_f4){0.f, 0.f, 0.f, 0.f};
#pragma unroll
    for (int ks = 0; ks < 2; ++ks) {
        int ko = ks * 64 + fq * 16;
        int Ra = i0 + fr;
        tre_bf8 afr = *(const tre_bf8*)(REb + Ra * 128 + (ko ^ ((Ra & 7) << 4)));
#pragma unroll
        for (int jf = 0; jf < 4; ++jf) {
            int Rb = (jf << 4) + fr;
            tre_bf8 bfr = *(const tre_bf8*)(Qtb + Rb * 128 + (ko ^ ((Rb & 7) << 4)));
            accA[jf] = __builtin_amdgcn_mfma_f32_16x16x32_bf16(afr, bfr, accA[jf], 0, 0, 0);
        }
    }
    __syncthreads();              // all REb reads done; reuse as Atb

    // store A transposed as bf16: Atb[col][row]
#pragma unroll
    for (int jf = 0; jf < 4; ++jf) {
        int C  = (jf << 4) + fr;
        int r0 = i0 + (fq << 2);
        int o  = r0 * 2;
        *(unsigned long long*)(sB + C * 128 + (o ^ ((C & 7) << 4))) =
            tre_pack4(accA[jf][0], accA[jf][1], accA[jf][2], accA[jf][3]);
    }
    __syncthreads();

    // pass 2: M = Q^T * A
    tre_f4 accM[4];
#pragma unroll
    for (int jf = 0; jf < 4; ++jf) accM[jf] = (tre_f4){0.f, 0.f, 0.f, 0.f};
#pragma unroll
    for (int ks = 0; ks < 2; ++ks) {
        int ko = ks * 64 + fq * 16;
        int Ra = i0 + fr;
        tre_bf8 afr = *(const tre_bf8*)(Qtb + Ra * 128 + (ko ^ ((Ra & 7) << 4)));
#pragma unroll
        for (int jf = 0; jf < 4; ++jf) {
            int Rb = (jf << 4) + fr;
            tre_bf8 bfr = *(const tre_bf8*)(sB + Rb * 128 + (ko ^ ((Rb & 7) << 4)));
            accM[jf] = __builtin_amdgcn_mfma_f32_16x16x32_bf16(afr, bfr, accM[jf], 0, 0, 0);
        }
    }
    __syncthreads();              // all bf16-tile reads done; reuse as M f32

    float* sM = (float*)sB;
#pragma unroll
    for (int jf = 0; jf < 4; ++jf) {
        int cc = (jf << 4) + fr;
        int r0 = i0 + (fq << 2);
        sM[(r0 + 0) * 64 + cc] = accM[jf][0];
        sM[(r0 + 1) * 64 + cc] = accM[jf][1];
        sM[(r0 + 2) * 64 + cc] = accM[jf][2];
        sM[(r0 + 3) * 64 + cc] = accM[jf][3];
    }
    __syncthreads();

#pragma unroll
    for (int j = 0; j < 4; ++j)
        mreg[j] = *(const tre_f4*)&sM[(t + 256 * j) << 2];
}

// ---------------------------------------------------------------------------
// Kernel 2 (persistent): pull buckets from the queue.  M inline; per bucket
// precompute BOTH sign variants (vp = I+eps*M, vm = I-eps*M) so the edge
// loop is pure NT stores + a block-uniform sign branch (no per-edge FMA).
__global__ __launch_bounds__(256, 4) void tre_pair(
    const float* __restrict__ Q, const float* __restrict__ RE,
    const int* __restrict__ counts, const int* __restrict__ list,
    int* __restrict__ cursor, float* __restrict__ out)
{
    __shared__ __align__(16) unsigned char sB[16384];
    __shared__ int sList[TRE_CAP];
    __shared__ int sTicket;

    const int t = threadIdx.x;

    int b = blockIdx.x;
    for (;;) {
        if (b >= TRE_NB) break;

        const int cnt_raw = counts[b];
        const int cnt = cnt_raw > TRE_CAP ? TRE_CAP : cnt_raw;

        if (cnt > 0) {
            tre_f4 mreg[4];
            if (t < cnt) sList[t] = list[b * TRE_CAP + t];
            tre_compute_M(b, Q, RE, sB, t, mreg);   // internal syncs cover sList

            // prefetch next ticket; latency hides under the write burst
            if (t == 0) sTicket = atomicAdd(cursor, 1);

            // hoist sign FMA out of the edge loop: both variants, once
            tre_f4 vp[4], vm[4];
#pragma unroll
            for (int j = 0; j < 4; ++j) {
                int f = (t + 256 * j) << 2;
                tre_f4 d;
#pragma unroll
                for (int c = 0; c < 4; ++c) {
                    int fc = f + c;
                    d[c] = ((fc >> 6) == (fc & 63)) ? 1.0f : 0.0f;
                }
                vp[j] = TRE_EPS * mreg[j] + d;
                vm[j] = -TRE_EPS * mreg[j] + d;
            }

            int pk = sList[0];
            for (int i = 0; i < cnt; ++i) {
                int nxt = (i + 1 < cnt) ? sList[i + 1] : 0;
                int e = pk >> 1;
                tre_f4* dst = (tre_f4*)(out + ((size_t)e << 12));
                if (pk & 1) {              // block-uniform -> scalar branch
#pragma unroll
                    for (int j = 0; j < 4; ++j)
                        __builtin_nontemporal_store(vm[j], &dst[t + 256 * j]);
                } else {
#pragma unroll
                    for (int j = 0; j < 4; ++j)
                        __builtin_nontemporal_store(vp[j], &dst[t + 256 * j]);
                }
                pk = nxt;
            }
        } else {
            if (t == 0) sTicket = atomicAdd(cursor, 1);
        }

        __syncthreads();              // sTicket ready; sB/sList reusable
        b = sTicket;
    }
}

// ---------------------------------------------------------------------------
// Fallback (ws too small): direct per-edge compute (round-1 verified path).
__global__ __launch_bounds__(256) void tre_direct(
    const int* __restrict__ rm, const float* __restrict__ Q,
    const float* __restrict__ RE, float* __restrict__ out)
{
    __shared__ float sQ[64 * 64];
    __shared__ float sW[64 * 65];

    const int e = blockIdx.x;
    const int g  = rm[2 * e + 0];
    const int r2 = rm[2 * e + 1];
    const int r  = r2 >> 1;
    const float s = (r2 & 1) ? -TRE_EPS : TRE_EPS;
    const int t = threadIdx.x;
    const int i0 = (t >> 4) << 2;
    const int l0 = (t & 15) << 2;

    const float* Qg  = Q  + ((size_t)g << 12);
    const float* REr = RE + ((size_t)r << 12);
    for (int i = t; i < 1024; i += 256) {
        ((float4*)sQ)[i] = ((const float4*)Qg)[i];
        float4 w = ((const float4*)REr)[i];
        int row = i >> 4, col = (i & 15) << 2;
        float* dst = &sW[row * 65 + col];
        dst[0] = w.x; dst[1] = w.y; dst[2] = w.z; dst[3] = w.w;
    }
    __syncthreads();

    float a[4][4] = {{0,0,0,0},{0,0,0,0},{0,0,0,0},{0,0,0,0}};
#pragma unroll 8
    for (int k = 0; k < 64; ++k) {
        float4 qv = *(const float4*)&sQ[(k << 6) + l0];
#pragma unroll
        for (int d = 0; d < 4; ++d) {
            float w = sW[(i0 + d) * 65 + k];
            a[d][0] = fmaf(w, qv.x, a[d][0]);
            a[d][1] = fmaf(w, qv.y, a[d][1]);
            a[d][2] = fmaf(w, qv.z, a[d][2]);
            a[d][3] = fmaf(w, qv.w, a[d][3]);
        }
    }
    __syncthreads();
    float* sA = sW;
#pragma unroll
    for (int d = 0; d < 4; ++d)
        *(float4*)&sA[(i0 + d) * 64 + l0] =
            make_float4(a[d][0], a[d][1], a[d][2], a[d][3]);
    __syncthreads();

    float qtq[4][4] = {{0,0,0,0},{0,0,0,0},{0,0,0,0},{0,0,0,0}};
    float qta[4][4] = {{0,0,0,0},{0,0,0,0},{0,0,0,0},{0,0,0,0}};
#pragma unroll 4
    for (int j = 0; j < 64; ++j) {
        float4 qi = *(const float4*)&sQ[(j << 6) + i0];
        float4 ql = *(const float4*)&sQ[(j << 6) + l0];
        float4 av = *(const float4*)&sA[(j << 6) + l0];
        float qiv[4] = {qi.x, qi.y, qi.z, qi.w};
        float qlv[4] = {ql.x, ql.y, ql.z, ql.w};
        float avv[4] = {av.x, av.y, av.z, av.w};
#pragma unroll
        for (int d = 0; d < 4; ++d)
#pragma unroll
            for (int ee = 0; ee < 4; ++ee) {
                qtq[d][ee] = fmaf(qiv[d], qlv[ee], qtq[d][ee]);
                qta[d][ee] = fmaf(qiv[d], avv[ee], qta[d][ee]);
            }
    }
    float* dst = out + ((size_t)e << 12);
#pragma unroll
    for (int d = 0; d < 4; ++d) {
        float4 v;
        v.x = fmaf(s, qta[d][0], qtq[d][0]);
        v.y = fmaf(s, qta[d][1], qtq[d][1]);
        v.z = fmaf(s, qta[d][2], qtq[d][2]);
        v.w = fmaf(s, qta[d][3], qtq[d][3]);
        *(float4*)&dst[(i0 + d) * 64 + l0] = v;
    }
}

extern "C" void kernel_launch(void* const* d_in, const int* in_sizes, int n_in,
                              void* d_out, int out_size, void* d_ws, size_t ws_size,
                              hipStream_t stream) {
    // Inputs: relation_mapping, node_mapping, edge_index, node_embs,
    //         relation_embs, Q.  (only rm, RE, Q feed the output)
    const int*   rm = (const int*)d_in[0];
    const float* RE = (const float*)d_in[4];
    const float* Q  = (const float*)d_in[5];
    float* out = (float*)d_out;
    const int E = in_sizes[0] / 2;

    // ws layout: counts (8 KB) | cursor (16 B) | list (2 MB)
    const size_t cnt_bytes  = (size_t)TRE_NB * sizeof(int);
    const size_t cur_bytes  = 16;
    const size_t list_bytes = (size_t)TRE_NB * TRE_CAP * sizeof(int);
    const size_t need = cnt_bytes + cur_bytes + list_bytes;

    if (ws_size >= need) {
        int* counts = (int*)d_ws;
        int* cursor = (int*)((char*)d_ws + cnt_bytes);
        int* list   = (int*)((char*)d_ws + cnt_bytes + cur_bytes);
        hipMemsetAsync(counts, 0, cnt_bytes + cur_bytes, stream);
        hipLaunchKernelGGL(tre_bin, dim3((E + 255) / 256), dim3(256), 0, stream,
                           rm, E, counts, list, cursor);
        hipLaunchKernelGGL(tre_pair, dim3(TRE_PGRID), dim3(256), 0, stream,
                           Q, RE, counts, list, cursor, out);
    } else {
        hipLaunchKernelGGL(tre_direct, dim3(E), dim3(256), 0, stream,
                           rm, Q, RE, out);
    }
}

// Round 15
// 111.795 us; speedup vs baseline: 1.0753x; 1.0753x over previous
//
#include <hip/hip_runtime.h>

#define TRE_EPS   0.01f
#define TRE_CAP   256
#define TRE_NB    2048   // 64 g-values * 32 r-values
#define TRE_PGRID 1024   // persistent blocks (4 per CU)

typedef float tre_f4 __attribute__((ext_vector_type(4)));
typedef short tre_bf8 __attribute__((ext_vector_type(8)));

__device__ __forceinline__ unsigned short tre_f2bf(float f) {
    unsigned int u = __float_as_uint(f);
    u += 0x7fffu + ((u >> 16) & 1u);           // RNE
    return (unsigned short)(u >> 16);
}
__device__ __forceinline__ unsigned long long tre_pack4(float a, float b,
                                                        float c, float d) {
    return (unsigned long long)tre_f2bf(a)
         | ((unsigned long long)tre_f2bf(b) << 16)
         | ((unsigned long long)tre_f2bf(c) << 32)
         | ((unsigned long long)tre_f2bf(d) << 48);
}

// ---------------------------------------------------------------------------
// Kernel 1: bin edges by (g, r) pair.  counts+cursor zeroed beforehand.
// Also seeds the persistent-queue cursor to TRE_PGRID.
__global__ __launch_bounds__(256) void tre_bin(
    const int* __restrict__ rm, int E,
    int* __restrict__ counts, int* __restrict__ list, int* __restrict__ cursor)
{
    if (blockIdx.x == 0 && threadIdx.x == 0) *cursor = TRE_PGRID;
    int e = blockIdx.x * 256 + threadIdx.x;
    if (e >= E) return;
    int g  = rm[2 * e + 0];
    int r2 = rm[2 * e + 1];
    int b  = (g << 5) | (r2 >> 1);
    int idx = atomicAdd(&counts[b], 1);
    if (idx < TRE_CAP)
        list[b * TRE_CAP + idx] = (e << 1) | (r2 & 1);
}

// M = Q[g]^T * RE[r] * Q[g] via bf16 MFMA; result -> mreg (thread's flat
// write-slice).  Uses sB (16 KB) with internal barriers.
__device__ __forceinline__ void tre_compute_M(
    int b, const float* __restrict__ Q, const float* __restrict__ RE,
    unsigned char* sB, int t, tre_f4 mreg[4])
{
    const int g = b >> 5;
    const int r = b & 31;
    const int lane = t & 63;
    const int wv = t >> 6;
    const int fr = lane & 15;
    const int fq = lane >> 4;
    const int i0 = wv << 4;

    const float* Qg  = Q  + ((size_t)g << 12);
    const float* REr = RE + ((size_t)r << 12);
    unsigned char* REb = sB;
    unsigned char* Qtb = sB + 8192;

    // stage RE -> bf16 row-major (swizzled)
    for (int i = t; i < 1024; i += 256) {
        float4 w = ((const float4*)REr)[i];
        int R = i >> 4, c0 = (i & 15) << 2;
        int o = c0 * 2;
        *(unsigned long long*)(REb + R * 128 + (o ^ ((R & 7) << 4))) =
            tre_pack4(w.x, w.y, w.z, w.w);
    }
    // stage Q^T -> bf16 (column-coalesced global reads)
    for (int it = 0; it < 4; ++it) {
        int k0 = (wv << 2) + (it << 4);
        float q0 = Qg[(k0 + 0) * 64 + lane];
        float q1 = Qg[(k0 + 1) * 64 + lane];
        float q2 = Qg[(k0 + 2) * 64 + lane];
        float q3 = Qg[(k0 + 3) * 64 + lane];
        int R = lane, o = k0 * 2;
        *(unsigned long long*)(Qtb + R * 128 + (o ^ ((R & 7) << 4))) =
            tre_pack4(q0, q1, q2, q3);
    }
    __syncthreads();

    // pass 1: A = RE * Q
    tre_f4 accA[4];
#pragma unroll
    for (int jf = 0; jf < 4; ++jf) accA[jf] = (tre_f4){0.f, 0.f, 0.f, 0.f};
#pragma unroll
    for (int ks = 0; ks < 2; ++ks) {
        int ko = ks * 64 + fq * 16;
        int Ra = i0 + fr;
        tre_bf8 afr = *(const tre_bf8*)(REb + Ra * 128 + (ko ^ ((Ra & 7) << 4)));
#pragma unroll
        for (int jf = 0; jf < 4; ++jf) {
            int Rb = (jf << 4) + fr;
            tre_bf8 bfr = *(const tre_bf8*)(Qtb + Rb * 128 + (ko ^ ((Rb & 7) << 4)));
            accA[jf] = __builtin_amdgcn_mfma_f32_16x16x32_bf16(afr, bfr, accA[jf], 0, 0, 0);
        }
    }
    __syncthreads();              // all REb reads done; reuse as Atb

    // store A transposed as bf16: Atb[col][row]
#pragma unroll
    for (int jf = 0; jf < 4; ++jf) {
        int C  = (jf << 4) + fr;
        int r0 = i0 + (fq << 2);
        int o  = r0 * 2;
        *(unsigned long long*)(sB + C * 128 + (o ^ ((C & 7) << 4))) =
            tre_pack4(accA[jf][0], accA[jf][1], accA[jf][2], accA[jf][3]);
    }
    __syncthreads();

    // pass 2: M = Q^T * A
    tre_f4 accM[4];
#pragma unroll
    for (int jf = 0; jf < 4; ++jf) accM[jf] = (tre_f4){0.f, 0.f, 0.f, 0.f};
#pragma unroll
    for (int ks = 0; ks < 2; ++ks) {
        int ko = ks * 64 + fq * 16;
        int Ra = i0 + fr;
        tre_bf8 afr = *(const tre_bf8*)(Qtb + Ra * 128 + (ko ^ ((Ra & 7) << 4)));
#pragma unroll
        for (int jf = 0; jf < 4; ++jf) {
            int Rb = (jf << 4) + fr;
            tre_bf8 bfr = *(const tre_bf8*)(sB + Rb * 128 + (ko ^ ((Rb & 7) << 4)));
            accM[jf] = __builtin_amdgcn_mfma_f32_16x16x32_bf16(afr, bfr, accM[jf], 0, 0, 0);
        }
    }
    __syncthreads();              // all bf16-tile reads done; reuse as M f32

    float* sM = (float*)sB;
#pragma unroll
    for (int jf = 0; jf < 4; ++jf) {
        int cc = (jf << 4) + fr;
        int r0 = i0 + (fq << 2);
        sM[(r0 + 0) * 64 + cc] = accM[jf][0];
        sM[(r0 + 1) * 64 + cc] = accM[jf][1];
        sM[(r0 + 2) * 64 + cc] = accM[jf][2];
        sM[(r0 + 3) * 64 + cc] = accM[jf][3];
    }
    __syncthreads();

#pragma unroll
    for (int j = 0; j < 4; ++j)
        mreg[j] = *(const tre_f4*)&sM[(t + 256 * j) << 2];
}

// ---------------------------------------------------------------------------
// Kernel 2 (persistent): 1024 blocks pull buckets from a global queue.
// Per bucket: M = Q^T*RE*Q via bf16 MFMA (computed ONCE), then
// out[e] = I + (+/- eps) * M for every edge (NT stores).  Ticket at bottom.
__global__ __launch_bounds__(256, 4) void tre_pair(
    const float* __restrict__ Q, const float* __restrict__ RE,
    const int* __restrict__ counts, const int* __restrict__ list,
    int* __restrict__ cursor, float* __restrict__ out)
{
    __shared__ __align__(16) unsigned char sB[16384];
    __shared__ int sList[TRE_CAP];
    __shared__ int sTicket;

    const int t = threadIdx.x;

    tre_f4 diag[4];
#pragma unroll
    for (int j = 0; j < 4; ++j) {
        int f = (t + 256 * j) << 2;
#pragma unroll
        for (int c = 0; c < 4; ++c) {
            int fc = f + c;
            diag[j][c] = ((fc >> 6) == (fc & 63)) ? 1.0f : 0.0f;
        }
    }

    int b = blockIdx.x;
    for (;;) {
        if (b >= TRE_NB) break;

        const int cnt_raw = counts[b];
        const int cnt = cnt_raw > TRE_CAP ? TRE_CAP : cnt_raw;

        if (cnt > 0) {
            tre_f4 mreg[4];
            if (t < cnt) sList[t] = list[b * TRE_CAP + t];
            tre_compute_M(b, Q, RE, sB, t, mreg);   // internal syncs cover sList

            int pk = sList[0];
            for (int i = 0; i < cnt; ++i) {
                int nxt = (i + 1 < cnt) ? sList[i + 1] : 0;
                int e = pk >> 1;
                float s = (pk & 1) ? -TRE_EPS : TRE_EPS;
                tre_f4* dst = (tre_f4*)(out + ((size_t)e << 12));
#pragma unroll
                for (int j = 0; j < 4; ++j) {
                    tre_f4 v = s * mreg[j] + diag[j];
                    __builtin_nontemporal_store(v, &dst[t + 256 * j]);
                }
                pk = nxt;
            }
        }

        __syncthreads();              // everyone done with sB/sList/sTicket
        if (t == 0) sTicket = atomicAdd(cursor, 1);
        __syncthreads();
        b = sTicket;
    }
}

// ---------------------------------------------------------------------------
// Fallback (ws too small): direct per-edge compute (round-1 verified path).
__global__ __launch_bounds__(256) void tre_direct(
    const int* __restrict__ rm, const float* __restrict__ Q,
    const float* __restrict__ RE, float* __restrict__ out)
{
    __shared__ float sQ[64 * 64];
    __shared__ float sW[64 * 65];

    const int e = blockIdx.x;
    const int g  = rm[2 * e + 0];
    const int r2 = rm[2 * e + 1];
    const int r  = r2 >> 1;
    const float s = (r2 & 1) ? -TRE_EPS : TRE_EPS;
    const int t = threadIdx.x;
    const int i0 = (t >> 4) << 2;
    const int l0 = (t & 15) << 2;

    const float* Qg  = Q  + ((size_t)g << 12);
    const float* REr = RE + ((size_t)r << 12);
    for (int i = t; i < 1024; i += 256) {
        ((float4*)sQ)[i] = ((const float4*)Qg)[i];
        float4 w = ((const float4*)REr)[i];
        int row = i >> 4, col = (i & 15) << 2;
        float* dst = &sW[row * 65 + col];
        dst[0] = w.x; dst[1] = w.y; dst[2] = w.z; dst[3] = w.w;
    }
    __syncthreads();

    float a[4][4] = {{0,0,0,0},{0,0,0,0},{0,0,0,0},{0,0,0,0}};
#pragma unroll 8
    for (int k = 0; k < 64; ++k) {
        float4 qv = *(const float4*)&sQ[(k << 6) + l0];
#pragma unroll
        for (int d = 0; d < 4; ++d) {
            float w = sW[(i0 + d) * 65 + k];
            a[d][0] = fmaf(w, qv.x, a[d][0]);
            a[d][1] = fmaf(w, qv.y, a[d][1]);
            a[d][2] = fmaf(w, qv.z, a[d][2]);
            a[d][3] = fmaf(w, qv.w, a[d][3]);
        }
    }
    __syncthreads();
    float* sA = sW;
#pragma unroll
    for (int d = 0; d < 4; ++d)
        *(float4*)&sA[(i0 + d) * 64 + l0] =
            make_float4(a[d][0], a[d][1], a[d][2], a[d][3]);
    __syncthreads();

    float qtq[4][4] = {{0,0,0,0},{0,0,0,0},{0,0,0,0},{0,0,0,0}};
    float qta[4][4] = {{0,0,0,0},{0,0,0,0},{0,0,0,0},{0,0,0,0}};
#pragma unroll 4
    for (int j = 0; j < 64; ++j) {
        float4 qi = *(const float4*)&sQ[(j << 6) + i0];
        float4 ql = *(const float4*)&sQ[(j << 6) + l0];
        float4 av = *(const float4*)&sA[(j << 6) + l0];
        float qiv[4] = {qi.x, qi.y, qi.z, qi.w};
        float qlv[4] = {ql.x, ql.y, ql.z, ql.w};
        float avv[4] = {av.x, av.y, av.z, av.w};
#pragma unroll
        for (int d = 0; d < 4; ++d)
#pragma unroll
            for (int ee = 0; ee < 4; ++ee) {
                qtq[d][ee] = fmaf(qiv[d], qlv[ee], qtq[d][ee]);
                qta[d][ee] = fmaf(qiv[d], avv[ee], qta[d][ee]);
            }
    }
    float* dst = out + ((size_t)e << 12);
#pragma unroll
    for (int d = 0; d < 4; ++d) {
        float4 v;
        v.x = fmaf(s, qta[d][0], qtq[d][0]);
        v.y = fmaf(s, qta[d][1], qtq[d][1]);
        v.z = fmaf(s, qta[d][2], qtq[d][2]);
        v.w = fmaf(s, qta[d][3], qtq[d][3]);
        *(float4*)&dst[(i0 + d) * 64 + l0] = v;
    }
}

extern "C" void kernel_launch(void* const* d_in, const int* in_sizes, int n_in,
                              void* d_out, int out_size, void* d_ws, size_t ws_size,
                              hipStream_t stream) {
    // Inputs: relation_mapping, node_mapping, edge_index, node_embs,
    //         relation_embs, Q.  (only rm, RE, Q feed the output)
    const int*   rm = (const int*)d_in[0];
    const float* RE = (const float*)d_in[4];
    const float* Q  = (const float*)d_in[5];
    float* out = (float*)d_out;
    const int E = in_sizes[0] / 2;

    // ws layout: counts (8 KB) | cursor (16 B) | list (2 MB)
    const size_t cnt_bytes  = (size_t)TRE_NB * sizeof(int);
    const size_t cur_bytes  = 16;
    const size_t list_bytes = (size_t)TRE_NB * TRE_CAP * sizeof(int);
    const size_t need = cnt_bytes + cur_bytes + list_bytes;

    if (ws_size >= need) {
        int* counts = (int*)d_ws;
        int* cursor = (int*)((char*)d_ws + cnt_bytes);
        int* list   = (int*)((char*)d_ws + cnt_bytes + cur_bytes);
        hipMemsetAsync(counts, 0, cnt_bytes + cur_bytes, stream);
        hipLaunchKernelGGL(tre_bin, dim3((E + 255) / 256), dim3(256), 0, stream,
                           rm, E, counts, list, cursor);
        hipLaunchKernelGGL(tre_pair, dim3(TRE_PGRID), dim3(256), 0, stream,
                           Q, RE, counts, list, cursor, out);
    } else {
        hipLaunchKernelGGL(tre_direct, dim3(E), dim3(256), 0, stream,
                           rm, Q, RE, out);
    }
}